// Round 1
// baseline (241.249 us; speedup 1.0000x reference)
//
#include <hip/hip_runtime.h>
#include <float.h>

// PQHead forward: out[b, m*6+d] = codebooks[m, argmax_k dot(x[b,m,:], cb[m,k,:]), d]
// (straight-through estimator: forward value of quant is exactly `discrete`)
//
// R7: kill the barrier coupling. Counters (R6): dur 107us, VALUBusy 43%,
// Occupancy 32%, HBM 19% -> latency-bound, not pipe-bound. The LDS stage
// existed only to broadcast 6 floats to a 4-lane quad; L1 does that natively
// (quad lanes hit the same lines, wave footprint = 384 B contiguous per row).
//  - No __shared__, no __syncthreads: waves fully independent.
//  - Per-wave software pipeline: x loads 2 rows ahead in registers.
//  - Winner gather skewed 1 row behind its store so gather latency hides
//    under the next row's dot/select chain.
//  - Dot + select + DPP quad-merge + fp64 near-tie fallback unchanged (proven).

typedef float v2f __attribute__((ext_vector_type(2)));

#define BATCH 32768
#define DIM   768
#define K_CB  32
#define D_SUB 6
#define BROWS 16               // rows per block
#define HALFF 384              // floats per half row (64 m * 6)

#define DPP_XOR1 0xB1          // quad_perm [1,0,3,2]
#define DPP_XOR2 0x4E          // quad_perm [2,3,0,1]

template<int CTRL>
__device__ __forceinline__ float dppf(float v) {
    return __int_as_float(__builtin_amdgcn_update_dpp(
        0, __float_as_int(v), CTRL, 0xF, 0xF, true));
}
template<int CTRL>
__device__ __forceinline__ int dppi(int v) {
    return __builtin_amdgcn_update_dpp(0, v, CTRL, 0xF, 0xF, true);
}

__global__ __launch_bounds__(256, 4)
void pq_head_kernel(const float* __restrict__ x,
                    const float* __restrict__ cb,
                    float* __restrict__ out) {
    const int t     = threadIdx.x;
    const int kq    = t & 3;        // k-quarter (lane within quad)
    const int mloc  = t >> 2;       // 0..63
    const int mhalf = blockIdx.y;   // 0/1
    const int m     = mhalf * 64 + mloc;
    const int b0    = blockIdx.x * BROWS;

    // Load this lane's 8 codebook rows (48 floats, 192-B aligned) and pack
    // code-pairs into v2f: cpk[p][e] = (cb[2p][e], cb[2p+1][e]).
    v2f cpk[4][D_SUB];
    {
        float cc[48];
        const float4* cb4 = reinterpret_cast<const float4*>(
            cb + ((size_t)m * K_CB + (size_t)kq * 8) * D_SUB);
        #pragma unroll
        for (int i = 0; i < 12; ++i) {
            float4 v = cb4[i];
            cc[4*i+0]=v.x; cc[4*i+1]=v.y; cc[4*i+2]=v.z; cc[4*i+3]=v.w;
        }
        #pragma unroll
        for (int p = 0; p < 4; ++p)
            #pragma unroll
            for (int e = 0; e < D_SUB; ++e)
                cpk[p][e] = (v2f){cc[(2*p)*D_SUB + e], cc[(2*p+1)*D_SUB + e]};
    }

    // Per-lane base pointers: this quad's 24-B x slice / output slice.
    const float* xb = x   + (size_t)b0 * DIM + (size_t)mhalf * HALFF + mloc * D_SUB;
    float*       ob = out + (size_t)b0 * DIM + (size_t)mhalf * HALFF + mloc * D_SUB;

    const bool act = (kq < 3);      // 3 float2 per quad cover the 6 outputs

    // Software pipeline: x held 2 rows deep in registers (depth covers the
    // ~200-300 cy L2 latency with one full row of compute in between).
    float2 pfx[2][3];
    #pragma unroll
    for (int i = 0; i < 2; ++i) {
        const float2* p = reinterpret_cast<const float2*>(xb + (size_t)i * DIM);
        pfx[i][0] = p[0]; pfx[i][1] = p[1]; pfx[i][2] = p[2];
    }

    float2 gv[2];                   // gather results, skewed one row

    #pragma unroll
    for (int r = 0; r < BROWS; ++r) {
        // Consume this row's x, immediately re-issue the slot for row r+2.
        float2 xa = pfx[r & 1][0];
        float2 xc = pfx[r & 1][1];
        float2 xe = pfx[r & 1][2];
        if (r + 2 < BROWS) {
            const float2* p = reinterpret_cast<const float2*>(xb + (size_t)(r + 2) * DIM);
            pfx[r & 1][0] = p[0]; pfx[r & 1][1] = p[1]; pfx[r & 1][2] = p[2];
        }

        float xv[6] = {xa.x, xa.y, xc.x, xc.y, xe.x, xe.y};
        v2f xxe[6];
        #pragma unroll
        for (int e = 0; e < 6; ++e) xxe[e] = (v2f){xv[e], xv[e]};

        // 8 packed dots + running (best1, best2, kg); first-wins on strict >.
        float best1 = -FLT_MAX, best2 = -FLT_MAX;
        int   kg    = kq * 8;
        #pragma unroll
        for (int p = 0; p < 4; ++p) {
            v2f acc = cpk[p][0] * xxe[0];
            #pragma unroll
            for (int e = 1; e < 6; ++e)
                acc = __builtin_elementwise_fma(cpk[p][e], xxe[e], acc);
            #pragma unroll
            for (int h = 0; h < 2; ++h) {         // j = 2p+h, ascending
                float d  = h ? acc.y : acc.x;
                bool  gt = d > best1;             // strict > => first wins
                best2 = gt ? best1 : fmaxf(best2, d);
                kg    = gt ? (kq * 8 + 2*p + h) : kg;
                best1 = gt ? d : best1;
            }
        }

        // Quad butterfly via DPP (pure VALU).
        {
            float o1 = dppf<DPP_XOR1>(best1);
            float o2 = dppf<DPP_XOR1>(best2);
            int   ok = dppi<DPP_XOR1>(kg);
            bool take = (o1 > best1) || (o1 == best1 && ok < kg);
            best2 = fmaxf(fminf(best1, o1), fmaxf(best2, o2));
            kg    = take ? ok : kg;
            best1 = fmaxf(best1, o1);
        }
        {
            float o1 = dppf<DPP_XOR2>(best1);
            float o2 = dppf<DPP_XOR2>(best2);
            int   ok = dppi<DPP_XOR2>(kg);
            bool take = (o1 > best1) || (o1 == best1 && ok < kg);
            best2 = fmaxf(fminf(best1, o1), fmaxf(best2, o2));
            kg    = take ? ok : kg;
            best1 = fmaxf(best1, o1);
        }

        // Near-tie (quad-uniform, ~0.1%): exact fp64 argmax over 32 codes.
        if (best1 - best2 < 1e-5f) {
            const float* crow = cb + (size_t)m * K_CB * D_SUB;
            double db = -1e300; int dkg = 0;
            for (int k2 = 0; k2 < K_CB; ++k2) {
                double sa = 0.0;
                for (int e = 0; e < 6; ++e)
                    sa = fma((double)crow[k2*6+e], (double)xv[e], sa);
                if (sa > db) { db = sa; dkg = k2; }
            }
            kg = dkg;
        }

        // Gather this row's winner (cb is L1-hot: 12 KiB per wave's m-set);
        // store it one row later so the latency hides under row r+1's chain.
        if (act)
            gv[r & 1] = *(reinterpret_cast<const float2*>(
                cb + ((size_t)m * K_CB + (size_t)kg) * D_SUB) + kq);

        if (r > 0 && act)
            *(reinterpret_cast<float2*>(ob + (size_t)(r - 1) * DIM) + kq)
                = gv[(r - 1) & 1];
    }
    if (act)
        *(reinterpret_cast<float2*>(ob + (size_t)(BROWS - 1) * DIM) + kq)
            = gv[(BROWS - 1) & 1];
}

extern "C" void kernel_launch(void* const* d_in, const int* in_sizes, int n_in,
                              void* d_out, int out_size, void* d_ws, size_t ws_size,
                              hipStream_t stream) {
    const float* x  = (const float*)d_in[0];   // (32768, 768) fp32
    const float* cb = (const float*)d_in[1];   // (128, 32, 6) fp32
    float* out = (float*)d_out;                // (32768, 768) fp32

    dim3 grid(BATCH / BROWS, 2);   // 2048 x 2 = 4096 blocks
    dim3 block(256);               // 64 m x 4 k-quarters
    hipLaunchKernelGGL(pq_head_kernel, grid, block, 0, stream, x, cb, out);
}